// Round 13
// baseline (445.079 us; speedup 1.0000x reference)
//
#include <hip/hip_runtime.h>
#include <cstdint>

#define ND 16384
#define BATCH 4096
#define CDIM 768
#define E_DD 131072
#define FD 256

typedef unsigned short u16;
typedef u16 u16x4 __attribute__((ext_vector_type(4)));
typedef u16 u16x8 __attribute__((ext_vector_type(8)));
typedef short s16x8 __attribute__((ext_vector_type(8)));
typedef float f32x4 __attribute__((ext_vector_type(4)));

__device__ __forceinline__ u16 f2bf(float x) {
  union { float f; uint32_t u; } v; v.f = x;
  uint32_t r = v.u + 0x7fffu + ((v.u >> 16) & 1u);
  return (u16)(r >> 16);
}
__device__ __forceinline__ float bf2f(u16 h) {
  union { float f; uint32_t u; } v; v.u = ((uint32_t)h) << 16;
  return v.f;
}

// Direct global->LDS DMA, 16B per lane, LDS dest = wave-uniform base + lane*16.
#define GLOAD_LDS16(gp, lp)                                                   \
  __builtin_amdgcn_global_load_lds(                                           \
      (__attribute__((address_space(1))) void*)(gp),                          \
      (__attribute__((address_space(3))) void*)(lp), 16, 0, 0)

// ---------------------------------------------------------------------------
// MFMA GEMM core (device fn), 128x128 tile, 16x16x32 MFMA.
// NW = waves/block: 4 (2x2 wave grid, 64x64/wave) or 8 (2x4, 64x32/wave).
// DIRECT path: global_load_lds double-buffered, BKD-wide K-step, both-sides
// XOR slot swizzle (R2: 0 bank conflicts at BKD=64). r2a at 913 TF == the
// m97-structure ceiling (m103: 912). Probed/excluded: counted-vmcnt (R3),
// XCD swizzle (R7), >4 waves/SIMD within a block (R8 +1%), gat merges
// (R5/R9). R12: hs as concat-K DIRECT GEMM (retired ASPLIT reg-staging,
// dual 74->~50). R13: dual upgraded to BK=64/NW=8 (the R2/R8-proven
// config; BK32's 64B rows span 16 banks -> 4-way conflicts + 2x drains).
// ---------------------------------------------------------------------------
template <int KS, int OUT_BF16, int RELU, int BIAS, int BKD, int NW>
__device__ __forceinline__ void gemm_core(
    int bx, int by, int bz,
    const u16* __restrict__ Ahi, const u16* __restrict__ Bhi,
    const float* __restrict__ bias,
    float* __restrict__ Cf, u16* __restrict__ Chi,
    int M, int N, int K, u16* AsB, u16* BsB) {
  constexpr int NTH = NW * 64;
  constexpr int WC = (NW == 8) ? 4 : 2;       // wave-grid cols
  constexpr int MT = 4;
  constexpr int NT = (NW == 8) ? 2 : 4;
  constexpr int BM = 128, BN = 128;

  const int t = threadIdx.x;
  const int bm0 = bx * BM, bn0 = by * BN;
  const int wid = t >> 6, lane = t & 63;
  const int quad = lane >> 4, l16 = lane & 15;
  const int wm0 = (wid / WC) * (MT * 16);
  const int wn0 = (wid % WC) * (NT * 16);

  const int chunk = K / KS;
  const int kbeg = (KS > 1) ? bz * chunk : 0;
  const int kend = kbeg + chunk;

  // Bias preload before the loop: off the epilogue critical path.
  float bvv[NT];
#pragma unroll
  for (int ni = 0; ni < NT; ++ni)
    bvv[ni] = BIAS ? bias[bn0 + wn0 + ni * 16 + l16] : 0.f;

  f32x4 acc[MT][NT];
#pragma unroll
  for (int i = 0; i < MT; ++i)
#pragma unroll
    for (int j = 0; j < NT; ++j) acc[i][j] = (f32x4){0.f, 0.f, 0.f, 0.f};

  // LDS: As/Bs [2][128][BKD] u16, linear in gload_lds lane order.
  // Swizzle: LDS 16B-slot (r, j) holds global chunk (r, j ^ (r & SM)).
  constexpr int SLOTS = BKD / 8;       // 16B chunks per row
  constexpr int SM = SLOTS - 1;
  constexpr int NLD = (BM * BKD) / (NTH * 8);  // gload_lds / thread / matrix
  auto stageA = [&](int buf, int kk) {
#pragma unroll
    for (int c = 0; c < NLD; ++c) {
      int s = t + NTH * c;
      int r = s / SLOTS, j = s % SLOTS;
      int jj = j ^ (r & SM);
      size_t goff = (size_t)(bm0 + r) * K + kk + jj * 8;
      int lofs = __builtin_amdgcn_readfirstlane((wid * 64 + NTH * c) * 8);
      GLOAD_LDS16(Ahi + goff, AsB + buf * (BM * BKD) + lofs);
    }
  };
  auto stageB = [&](int buf, int kk) {
#pragma unroll
    for (int c = 0; c < NLD; ++c) {
      int s = t + NTH * c;
      int r = s / SLOTS, j = s % SLOTS;
      int jj = j ^ (r & SM);
      size_t goff = (size_t)(bn0 + r) * K + kk + jj * 8;
      int lofs = __builtin_amdgcn_readfirstlane((wid * 64 + NTH * c) * 8);
      GLOAD_LDS16(Bhi + goff, BsB + buf * (BN * BKD) + lofs);
    }
  };
  const int rsw = l16 & SM;  // row&SM for all frag rows (rows ≡ l16 mod SLOTS)
  stageA(0, kbeg);
  stageB(0, kbeg);
  int cur = 0;
  for (int k0 = kbeg;;) {
    // __syncthreads drains vmcnt(0): buf[cur] staged, prior ds_reads done.
    __syncthreads();
    int kn = k0 + BKD;
    if (kn < kend) {  // prefetch next tile; in flight across the MFMA phase
      stageA(cur ^ 1, kn);
      stageB(cur ^ 1, kn);
    }
    const u16* Ab = AsB + cur * (BM * BKD);
    const u16* Bb = BsB + cur * (BN * BKD);
#pragma unroll
    for (int h = 0; h < BKD / 32; ++h) {
      s16x8 ah[MT], bh[NT];
#pragma unroll
      for (int mi = 0; mi < MT; ++mi)
        ah[mi] = *(const s16x8*)(Ab + (wm0 + mi * 16 + l16) * BKD +
                                 (((h * 4 + quad) ^ rsw) * 8));
#pragma unroll
      for (int ni = 0; ni < NT; ++ni)
        bh[ni] = *(const s16x8*)(Bb + (wn0 + ni * 16 + l16) * BKD +
                                 (((h * 4 + quad) ^ rsw) * 8));
#pragma unroll
      for (int mi = 0; mi < MT; ++mi)
#pragma unroll
        for (int ni = 0; ni < NT; ++ni)
          acc[mi][ni] = __builtin_amdgcn_mfma_f32_16x16x32_bf16(
              ah[mi], bh[ni], acc[mi][ni], 0, 0, 0);
    }
    k0 = kn;
    cur ^= 1;
    if (k0 >= kend) break;
  }

  // D row = quad*4 + reg, col = l16 (m89/m91 layout)
  float* Cp = (KS > 1) ? Cf + (size_t)bz * M * N : Cf;
#pragma unroll
  for (int mi = 0; mi < MT; ++mi) {
#pragma unroll
    for (int ni = 0; ni < NT; ++ni) {
      int row = bm0 + wm0 + mi * 16 + quad * 4;
      int col = bn0 + wn0 + ni * 16 + l16;
#pragma unroll
      for (int r = 0; r < 4; ++r) {
        float v = acc[mi][ni][r] + bvv[ni];
        if (RELU) v = fmaxf(v, 0.f);
        size_t o = (size_t)(row + r) * N + col;
        if (OUT_BF16) Chi[o] = f2bf(v);
        else Cp[o] = v;
      }
    }
  }
}

// Standalone GEMM kernel (no block swizzle — R7 lesson: default mapping wins).
template <int KS, int OUT_BF16, int RELU, int BIAS, int BKD, int NW>
__global__ __launch_bounds__(NW * 64) void mfma_gemm(
    const u16* __restrict__ Ahi, const u16* __restrict__ Bhi,
    const float* __restrict__ bias,
    float* __restrict__ Cf, u16* __restrict__ Chi,
    int M, int N, int K) {
  __shared__ __align__(16) u16 AsB[2 * 128 * BKD];
  __shared__ __align__(16) u16 BsB[2 * 128 * BKD];
  gemm_core<KS, OUT_BF16, RELU, BIAS, BKD, NW>(
      blockIdx.x, blockIdx.y, (KS > 1) ? (int)blockIdx.z : 0,
      Ahi, Bhi, bias, Cf, Chi, M, N, K, AsB, BsB);
}

// ---------------------------------------------------------------------------
// GAT aggregation body (device fn). One wave per dst; shuffle reductions;
// bf16 hs/out with wide loads (u16x8 + u16x4 = 24B/lane/row).
// ---------------------------------------------------------------------------
__device__ __forceinline__ void gat_body(
    int idx, int t,
    const u16* __restrict__ hs, const float* __restrict__ es,
    const float* __restrict__ ed, const int* __restrict__ offsets,
    const int* __restrict__ slots, const float* __restrict__ bias,
    const int* __restrict__ list, const int* __restrict__ cnt,
    u16* __restrict__ out) {
  if (idx >= *cnt) return;
  int d = list[idx];
  int lane = t & 63;
  int beg = offsets[d], end = offsets[d + 1];
  float edv = ed[d];
  float mx = -1e30f;
  for (int j = beg + lane; j < end; j += 64) {
    float e = es[slots[j]] + edv;
    e = e >= 0.f ? e : 0.2f * e;
    mx = fmaxf(mx, e);
  }
#pragma unroll
  for (int m = 32; m; m >>= 1) mx = fmaxf(mx, __shfl_xor(mx, m));
  float sm = 0.f;
  for (int j = beg + lane; j < end; j += 64) {
    float e = es[slots[j]] + edv;
    e = e >= 0.f ? e : 0.2f * e;
    sm += expf(e - mx);
  }
#pragma unroll
  for (int m = 32; m; m >>= 1) sm += __shfl_xor(sm, m);
  float inv = 1.f / (sm + 1e-16f);
  int c8 = lane * 8;          // cols 0..511
  int c4 = 512 + lane * 4;    // cols 512..767
  float a8[8] = {};
  float a4[4] = {};
  for (int j = beg; j < end; ++j) {
    int srcn = slots[j];
    float e = es[srcn] + edv;
    e = e >= 0.f ? e : 0.2f * e;
    float alpha = expf(e - mx) * inv;
    const u16* hrow = hs + (size_t)srcn * CDIM;
    u16x8 r8 = *(const u16x8*)(hrow + c8);
    u16x4 r4 = *(const u16x4*)(hrow + c4);
#pragma unroll
    for (int e2 = 0; e2 < 8; ++e2) a8[e2] = fmaf(alpha, bf2f(r8[e2]), a8[e2]);
#pragma unroll
    for (int e2 = 0; e2 < 4; ++e2) a4[e2] = fmaf(alpha, bf2f(r4[e2]), a4[e2]);
  }
  u16* orow = out + (size_t)d * CDIM;
  u16x8 o8;
  u16x4 o4;
#pragma unroll
  for (int e2 = 0; e2 < 8; ++e2) o8[e2] = f2bf(fmaxf(a8[e2] + bias[c8 + e2], 0.f));
#pragma unroll
  for (int e2 = 0; e2 < 4; ++e2) o4[e2] = f2bf(fmaxf(a4[e2] + bias[c4 + e2], 0.f));
  *(u16x8*)(orow + c8) = o8;
  *(u16x4*)(orow + c4) = o4;
}

__global__ __launch_bounds__(256) void gat_aggregate(
    const u16* __restrict__ hs, const float* __restrict__ es,
    const float* __restrict__ ed, const int* __restrict__ offsets,
    const int* __restrict__ slots, const float* __restrict__ bias,
    const int* __restrict__ list, const int* __restrict__ cnt,
    u16* __restrict__ out) {
  gat_body(blockIdx.x * 4 + (threadIdx.x >> 6), threadIdx.x,
           hs, es, ed, offsets, slots, bias, list, cnt, out);
}

// ---------------------------------------------------------------------------
// DUAL+SCATTER launch (R13: BK=64/NW=8 — per-block schedule identical to the
// R8-proven 913 TF config): red1 (blocks 0..511) + hs2 concat-K (512..1279)
// + edge scatter (1280..1535, 512 threads each). 64KB arena -> 2 blocks/CU.
// ---------------------------------------------------------------------------
__global__ __launch_bounds__(512) void dual_gemm_red1_hs_scatter(
    const u16* __restrict__ cn, const u16* __restrict__ r1T,
    const float* __restrict__ red1_b, u16* __restrict__ c1,
    const u16* __restrict__ x2, const u16* __restrict__ wsrcT2,
    u16* __restrict__ hs,
    const int* __restrict__ src, const int* __restrict__ dst,
    int* __restrict__ cursor, int* __restrict__ slots) {
  __shared__ __align__(16) u16 SMEM[32768];  // 64 KB
  int b = blockIdx.x;
  if (b < 512) {
    // red1: M=4096, N=2048, K=896 (14x64); grid 32 x 16
    gemm_core<1, 1, 1, 1, 64, 8>(b & 31, b >> 5, 0, cn, r1T, red1_b,
                                 nullptr, c1, BATCH, 2048, 896,
                                 SMEM, SMEM + 2 * 128 * 64);
  } else if (b < 1280) {
    // hs2: M=16384, N=768, K=512 (8x64, concat hi||lo); grid 128 x 6
    int b2 = b - 512;
    gemm_core<1, 1, 0, 0, 64, 8>(b2 & 127, b2 >> 7, 0, x2, wsrcT2, nullptr,
                                 nullptr, hs, ND, CDIM, 512,
                                 SMEM, SMEM + 2 * 128 * 64);
  } else {
    // scatter: CSR edge placement (256 blocks x 512 threads = E_DD)
    int e = (b - 1280) * 512 + threadIdx.x;
    if (e < E_DD) {
      int pos = atomicAdd(&cursor[dst[e]], 1);
      slots[pos] = src[e];
    }
  }
}

// ---------------------------------------------------------------------------
// Split-K reduce: sum KS fp32 partials, +bias, relu, round to bf16.
// ---------------------------------------------------------------------------
template <int KS>
__global__ void reduce_split_ks(const float* __restrict__ P,
                                const float* __restrict__ bias,
                                u16* __restrict__ Chi, int M, int N) {
  int i = blockIdx.x * 256 + threadIdx.x;
  int total = (M * N) >> 2;
  if (i >= total) return;
  f32x4 s = ((const f32x4*)P)[i];
#pragma unroll
  for (int z = 1; z < KS; ++z) s += ((const f32x4*)P)[(size_t)z * total + i];
  int col = (i * 4) % N;
  f32x4 bv = *(const f32x4*)(bias + col);
  u16x4 h;
#pragma unroll
  for (int e = 0; e < 4; ++e) h[e] = f2bf(fmaxf(s[e] + bv[e], 0.f));
  *(u16x4*)&Chi[i * 4] = h;
}

// ---------------------------------------------------------------------------
// r2c reduce fused with classifier. One wave per row.
// ---------------------------------------------------------------------------
__global__ void reduce_cls(const float* __restrict__ P,
                           const float* __restrict__ bias,
                           const float* __restrict__ clsw,
                           const float* __restrict__ clsb,
                           float* __restrict__ out) {
  int row = blockIdx.x * 4 + (threadIdx.x >> 6);
  int lane = threadIdx.x & 63;
  const f32x4* p0 = (const f32x4*)(P + (size_t)row * CDIM);
  const f32x4* p1 = (const f32x4*)(P + (size_t)BATCH * CDIM + (size_t)row * CDIM);
  float s0 = 0.f, s1 = 0.f;
#pragma unroll
  for (int i = 0; i < 3; ++i) {
    int c4 = lane + 64 * i;
    f32x4 a = p0[c4] + p1[c4];
    f32x4 bv = *(const f32x4*)(bias + c4 * 4);
#pragma unroll
    for (int e = 0; e < 4; ++e) {
      float h = fmaxf(a[e] + bv[e], 0.f);
      int c = c4 * 4 + e;
      s0 = fmaf(h, clsw[c * 2 + 0], s0);
      s1 = fmaf(h, clsw[c * 2 + 1], s1);
    }
  }
#pragma unroll
  for (int m = 32; m; m >>= 1) {
    s0 += __shfl_xor(s0, m);
    s1 += __shfl_xor(s1, m);
  }
  if (lane == 0) {
    out[row * 2 + 0] = s0 + clsb[0];
    out[row * 2 + 1] = s1 + clsb[1];
  }
}

// ---------------------------------------------------------------------------
// Weight-transpose descriptors: W fp32 [K][N] -> bf16 [N][Kpad].
// dup=1: additionally write each value at k+K (builds B2=[B||B], Kpad=2K).
// ---------------------------------------------------------------------------
struct TDesc {
  const float* W;
  u16* Th;
  int K, N, Kpad, start, dup;
};
struct TPack { TDesc d[7]; };

// ---------------------------------------------------------------------------
// PREP1 (merged, independent ops): blocks [0,11328) 7 weight transposes;
// [11328,11584) wvec; [11584,11648) csr-init; [11648,15744) cell l2norm.
// ---------------------------------------------------------------------------
#define P1_T 11328
#define P1_W (P1_T + 256)
#define P1_I (P1_W + 64)
__global__ __launch_bounds__(256) void prep1(
    TPack p,
    const float* __restrict__ Wsrc, const float* __restrict__ Wdst,
    const float* __restrict__ a_s, const float* __restrict__ a_d,
    float* __restrict__ wsv, float* __restrict__ wdv,
    int* __restrict__ counts, int* __restrict__ mask, int* __restrict__ cnt,
    const float* __restrict__ cellf, u16* __restrict__ cn_hi) {
  __shared__ __align__(16) float S[1088];  // 4352 B arena (max branch: 32x33 tile)
  int b = blockIdx.x;
  int t = threadIdx.x;
  if (b < P1_T) {
    // --- weight transpose ---
    float (*tile)[33] = (float(*)[33])S;
    int mi = 0;
#pragma unroll
    for (int i = 1; i < 7; ++i)
      if (b >= p.d[i].start) mi = i;
    TDesc dd = p.d[mi];
    int rel = b - dd.start;
    int tilesX = dd.dup ? (dd.K / 32) : (dd.Kpad / 32);
    int k0 = (rel % tilesX) * 32, n0 = (rel / tilesX) * 32;
    int tx = t & 31, ty = t >> 5;
#pragma unroll
    for (int i = 0; i < 4; ++i) {
      int k = k0 + ty + 8 * i, n = n0 + tx;
      tile[ty + 8 * i][tx] = (k < dd.K && n < dd.N) ? dd.W[(size_t)k * dd.N + n] : 0.f;
    }
    __syncthreads();
#pragma unroll
    for (int i = 0; i < 4; ++i) {
      int n = n0 + ty + 8 * i, k = k0 + tx;
      if (n < dd.N) {
        u16 v = f2bf(tile[tx][ty + 8 * i]);
        dd.Th[(size_t)n * dd.Kpad + k] = v;
        if (dd.dup) dd.Th[(size_t)n * dd.Kpad + k + dd.K] = v;
      }
    }
  } else if (b < P1_W) {
    // --- wvec: wsv[k] = W_src[k,:].a_src ; wdv[k] = W_dst[k,:].a_dst ---
    int k = b - P1_T;
    float* rs = S;
    float* rd = S + 256;
    float s = 0.f, d = 0.f;
    for (int c = t; c < CDIM; c += 256) {
      s += Wsrc[(size_t)k * CDIM + c] * a_s[c];
      d += Wdst[(size_t)k * CDIM + c] * a_d[c];
    }
    rs[t] = s; rd[t] = d;
    __syncthreads();
    for (int st = 128; st; st >>= 1) {
      if (t < st) { rs[t] += rs[t + st]; rd[t] += rd[t + st]; }
      __syncthreads();
    }
    if (t == 0) { wsv[k] = rs[0]; wdv[k] = rd[0]; }
  } else if (b < P1_I) {
    // --- csr init: counts=1 (self loop), mask=0, cnt=0 ---
    int i = (b - P1_W) * 256 + t;
    if (i < ND) { counts[i] = 1; mask[i] = 0; }
    if (i == 0) *cnt = 0;
  } else {
    // --- cell l2norm -> bf16 [BATCH][896], zero pad 890..896 ---
    int row = b - P1_I;
    float* red = S;
    const float* irow = cellf + (size_t)row * 890;
    float s = 0.f;
    for (int c = t; c < 890; c += 256) { float v = irow[c]; s += v * v; }
    red[t] = s;
    __syncthreads();
    for (int st = 128; st; st >>= 1) {
      if (t < st) red[t] += red[t + st];
      __syncthreads();
    }
    float inv = 1.f / fmaxf(sqrtf(red[0]), 1e-12f);
    for (int c = t; c < 896; c += 256) {
      float v = (c < 890) ? irow[c] * inv : 0.f;
      cn_hi[(size_t)row * 896 + c] = f2bf(v);
    }
  }
}

// ---------------------------------------------------------------------------
// PREP2 (needs prep1): blocks [0,4096) esed (needs wvec) + x2 hi/lo split
// (rides along); [4096,4112) mark; [4112,4624) count_edges.
// ---------------------------------------------------------------------------
#define P2_E (ND * FD / 1024)          // 4096
#define P2_M (P2_E + BATCH / 256)      // 4112
__global__ __launch_bounds__(256) void prep2(
    const float* __restrict__ x, const float* __restrict__ wsv,
    const float* __restrict__ wdv, float* __restrict__ es, float* __restrict__ ed,
    u16* __restrict__ x2,
    const int* __restrict__ d1, const int* __restrict__ d2, int* __restrict__ mask,
    const int* __restrict__ dst, int* __restrict__ counts) {
  int b = blockIdx.x, t = threadIdx.x;
  if (b < P2_E) {
    // --- esed: es[row]=x[row].wsv, ed[row]=x[row].wdv — one wave per row ---
    int i = b * 256 + t;  // float4 index
    int lane = t & 63;
    int row = i >> 6;
    int c4 = lane * 4;
    f32x4 v = ((const f32x4*)x)[i];
    f32x4 ws = *(const f32x4*)(wsv + c4);
    f32x4 wd = *(const f32x4*)(wdv + c4);
    float a = v[0] * ws[0] + v[1] * ws[1] + v[2] * ws[2] + v[3] * ws[3];
    float bb = v[0] * wd[0] + v[1] * wd[1] + v[2] * wd[2] + v[3] * wd[3];
    // hi/lo split for the concat-K hs GEMM (identical values to old split2p)
    u16x4 hi, lo;
#pragma unroll
    for (int e = 0; e < 4; ++e) {
      u16 h = f2bf(v[e]);
      hi[e] = h;
      lo[e] = f2bf(v[e] - bf2f(h));
    }
    *(u16x4*)(x2 + (size_t)row * 512 + c4) = hi;
    *(u16x4*)(x2 + (size_t)row * 512 + 256 + c4) = lo;
#pragma unroll
    for (int m = 32; m; m >>= 1) {
      a += __shfl_xor(a, m);
      bb += __shfl_xor(bb, m);
    }
    if (lane == 0) { es[row] = a; ed[row] = bb; }
  } else if (b < P2_M) {
    // --- mark needed dsts ---
    int i = (b - P2_E) * 256 + t;
    mask[d1[i]] = 1;
    mask[d2[i]] = 1;
  } else {
    // --- count edges per dst ---
    int e = (b - P2_M) * 256 + t;
    atomicAdd(&counts[dst[e]], 1);
  }
}

// ---------------------------------------------------------------------------
// PREP3 (needs prep2), 512 threads: blocks [0,32) compact; block 32 scan
// (+ self-loop head placement + cursor init).
// ---------------------------------------------------------------------------
__global__ __launch_bounds__(512) void prep3(
    const int* __restrict__ mask, int* __restrict__ cnt, int* __restrict__ list,
    const int* __restrict__ counts, int* __restrict__ offsets,
    int* __restrict__ cursor, int* __restrict__ slots) {
  __shared__ int part[512];
  int b = blockIdx.x, t = threadIdx.x;
  if (b < 32) {
    int i = b * 512 + t;
    if (mask[i]) {
      int pos = atomicAdd(cnt, 1);
      list[pos] = i;
    }
  } else {
    int base = t * 32;
    int s = 0;
    for (int i = 0; i < 32; ++i) s += counts[base + i];
    part[t] = s;
    __syncthreads();
    if (t == 0) {
      int run = 0;
      for (int i = 0; i < 512; ++i) { int tmp = part[i]; part[i] = run; run += tmp; }
      offsets[ND] = run;
    }
    __syncthreads();
    int run = part[t];
    for (int i = 0; i < 32; ++i) {
      int d = base + i;
      offsets[d] = run;
      slots[run] = d;
      cursor[d] = run + 1;
      run += counts[d];
    }
  }
}

// hidden = l2norm(concat(drug[d1], drug[d2], cell3)) -> bf16 [B][3072]
__global__ __launch_bounds__(256) void hidden_build_bf16(
    const u16* __restrict__ drug, const u16* __restrict__ c3,
    const int* __restrict__ d1, const int* __restrict__ d2,
    u16* __restrict__ hhi) {
  int row = blockIdx.x;
  int t = threadIdx.x;
  const u16* s1 = drug + (size_t)d1[row] * CDIM;
  const u16* s2 = drug + (size_t)d2[row] * CDIM;
  const u16* s3 = c3 + (size_t)row * (2 * CDIM);
  float vals[12];
  float ss = 0.f;
#pragma unroll
  for (int i = 0; i < 12; ++i) {
    int c = t + 256 * i;
    float v;
    if (i < 3)      v = bf2f(s1[c]);
    else if (i < 6) v = bf2f(s2[c - CDIM]);
    else            v = bf2f(s3[c - 2 * CDIM]);
    vals[i] = v;
    ss += v * v;
  }
  __shared__ float red[256];
  red[t] = ss;
  __syncthreads();
  for (int st = 128; st; st >>= 1) {
    if (t < st) red[t] += red[t + st];
    __syncthreads();
  }
  float inv = 1.f / fmaxf(sqrtf(red[0]), 1e-12f);
  u16* hrow_h = hhi + (size_t)row * (4 * CDIM);
#pragma unroll
  for (int i = 0; i < 12; ++i) hrow_h[t + 256 * i] = f2bf(vals[i] * inv);
}

// ---------------------------------------------------------------------------
extern "C" void kernel_launch(void* const* d_in, const int* in_sizes, int n_in,
                              void* d_out, int out_size, void* d_ws, size_t ws_size,
                              hipStream_t stream) {
  const float* x_drug   = (const float*)d_in[0];
  const float* cellf    = (const float*)d_in[2];
  const float* W_src_dd = (const float*)d_in[3];
  const float* W_dst_dd = (const float*)d_in[4];
  const float* a_src_dd = (const float*)d_in[5];
  const float* a_dst_dd = (const float*)d_in[6];
  const float* b_dd     = (const float*)d_in[7];
  const float* red1_w = (const float*)d_in[18];
  const float* red1_b = (const float*)d_in[19];
  const float* red2_w = (const float*)d_in[20];
  const float* red2_b = (const float*)d_in[21];
  const float* red3_w = (const float*)d_in[22];
  const float* red3_b = (const float*)d_in[23];
  const float* r2a_w  = (const float*)d_in[24];
  const float* r2a_b  = (const float*)d_in[25];
  const float* r2b_w  = (const float*)d_in[26];
  const float* r2b_b  = (const float*)d_in[27];
  const float* r2c_w  = (const float*)d_in[28];
  const float* r2c_b  = (const float*)d_in[29];
  const float* cls_w  = (const float*)d_in[30];
  const float* cls_b  = (const float*)d_in[31];
  const int* drug1_id = (const int*)d_in[32];
  const int* drug2_id = (const int*)d_in[33];
  const int* ei_dd    = (const int*)d_in[34];
  float* out = (float*)d_out;

  const int* dd_src = ei_dd;
  const int* dd_dst = ei_dd + E_DD;

  char* w = (char*)d_ws;
  size_t off = 0;
  auto alloc = [&](size_t bytes) -> char* {
    char* p = w + off;
    off = (off + bytes + 255) & ~(size_t)255;
    return p;
  };
  // bf16 intermediates (all re-rounded downstream; validated error ladder)
  u16* hs   = (u16*)alloc((size_t)ND * CDIM * 2);            // reused as hidden bf16
  u16* drug = (u16*)alloc((size_t)ND * CDIM * 2);
  u16* c3   = (u16*)alloc((size_t)BATCH * 2 * CDIM * 2);
  float* P  = (float*)alloc((size_t)4 * BATCH * 512 * 4);    // split-K partials
  u16* hid_hi = hs;  // alias: ND*CDIM == BATCH*4*CDIM
  // bf16 activations
  u16* cn_hi = (u16*)alloc((size_t)BATCH * 896 * 2);
  u16* c1_hi = (u16*)alloc((size_t)BATCH * 2048 * 2);        // shared with h1
  u16* c2_hi = (u16*)alloc((size_t)BATCH * 512 * 2);         // shared with h2
  // x_drug hi/lo concat [ND][512] for the hs concat-K GEMM (R12)
  u16* x2 = (u16*)alloc((size_t)ND * 512 * 2);
  // transposed weights [N][Kpad] — single bf16
  u16* wsrcT2 = (u16*)alloc((size_t)CDIM * 512 * 2);         // B2 = [B||B]
  u16* r1T_hi = (u16*)alloc((size_t)2048 * 896 * 2);
  u16* r2T_hi = (u16*)alloc((size_t)512 * 2048 * 2);
  u16* r3T_hi = (u16*)alloc((size_t)1536 * 512 * 2);
  u16* raT_hi = (u16*)alloc((size_t)2048 * 3072 * 2);
  u16* rbT_hi = (u16*)alloc((size_t)512 * 2048 * 2);
  u16* rcT_hi = (u16*)alloc((size_t)768 * 512 * 2);
  // GAT scalars / CSR / dst-compaction
  float* es  = (float*)alloc((size_t)ND * 4);
  float* ed  = (float*)alloc((size_t)ND * 4);
  float* wsv = (float*)alloc(FD * 4);
  float* wdv = (float*)alloc(FD * 4);
  int* counts  = (int*)alloc((size_t)ND * 4);
  int* offsets = (int*)alloc((size_t)(ND + 1) * 4);
  int* cursor  = (int*)alloc((size_t)ND * 4);
  int* slots   = (int*)alloc((size_t)(E_DD + ND) * 4);
  int* mask    = (int*)alloc((size_t)ND * 4);
  int* list    = (int*)alloc((size_t)ND * 4);
  int* cnt     = (int*)alloc(256);
  (void)ws_size; (void)n_in; (void)in_sizes; (void)out_size;

  // --- prep1: 7 transposes + wvec + csr-init + cell l2norm (one launch) ---
  // d[0] builds B2=[B||B] via dup (192 blocks: tilesX = K/32 = 8).
  TPack tp;
  tp.d[0] = {W_src_dd, wsrcT2, 256, 768, 512, 0, 1};
  tp.d[1] = {red1_w, r1T_hi, 890, 2048, 896, 192, 0};
  tp.d[2] = {red2_w, r2T_hi, 2048, 512, 2048, 1984, 0};
  tp.d[3] = {red3_w, r3T_hi, 512, 1536, 512, 3008, 0};
  tp.d[4] = {r2a_w, raT_hi, 3072, 2048, 3072, 3776, 0};
  tp.d[5] = {r2b_w, rbT_hi, 2048, 512, 2048, 9920, 0};
  tp.d[6] = {r2c_w, rcT_hi, 512, 768, 512, 10944, 0};
  prep1<<<15744, 256, 0, stream>>>(tp, W_src_dd, W_dst_dd, a_src_dd, a_dst_dd,
                                   wsv, wdv, counts, mask, cnt, cellf, cn_hi);

  // --- prep2: esed + x2 hi/lo split + mark + count (one launch) ---
  prep2<<<4624, 256, 0, stream>>>(x_drug, wsv, wdv, es, ed, x2, drug1_id,
                                  drug2_id, mask, dd_dst, counts);

  // --- prep3: compact + scan (one launch, 512 threads) ---
  prep3<<<33, 512, 0, stream>>>(mask, cnt, list, counts, offsets, cursor, slots);

  // --- DUAL+SCATTER: red1 + hs2 (both BK64/NW8) + edge scatter ---
  dual_gemm_red1_hs_scatter<<<1536, 512, 0, stream>>>(
      cn_hi, r1T_hi, red1_b, c1_hi, x2, wsrcT2, hs,
      dd_src, dd_dst, cursor, slots);

  // --- cell MLP tail (8-wave blocks: 4 waves/SIMD latency hiding) ---
  mfma_gemm<4, 0, 0, 0, 64, 8><<<dim3(BATCH / 128, 512 / 128, 4), 512, 0, stream>>>(
      c1_hi, r2T_hi, nullptr, P, nullptr, BATCH, 512, 2048);
  reduce_split_ks<4><<<BATCH * 512 / 1024, 256, 0, stream>>>(P, red2_b, c2_hi, BATCH, 512);
  mfma_gemm<1, 1, 1, 1, 64, 8><<<dim3(BATCH / 128, 1536 / 128), 512, 0, stream>>>(
      c2_hi, r3T_hi, red3_b, nullptr, c3, BATCH, 1536, 512);

  // --- GAT aggregation (softmax-weighted gather over CSR) ---
  gat_aggregate<<<ND / 4, 256, 0, stream>>>(hs, es, ed, offsets, slots, b_dd, list, cnt, drug);

  // --- gather + concat + l2norm -> bf16 (hidden aliases hs) ---
  hidden_build_bf16<<<BATCH, 256, 0, stream>>>(drug, c3, drug1_id, drug2_id, hid_hi);

  // --- head MLP (8-wave blocks) ---
  mfma_gemm<1, 1, 1, 1, 64, 8><<<dim3(BATCH / 128, 2048 / 128), 512, 0, stream>>>(
      hid_hi, raT_hi, r2a_b, nullptr, c1_hi, BATCH, 2048, 3072);
  mfma_gemm<4, 0, 0, 0, 64, 8><<<dim3(BATCH / 128, 512 / 128, 4), 512, 0, stream>>>(
      c1_hi, rbT_hi, nullptr, P, nullptr, BATCH, 512, 2048);
  reduce_split_ks<4><<<BATCH * 512 / 1024, 256, 0, stream>>>(P, r2b_b, c2_hi, BATCH, 512);
  mfma_gemm<2, 0, 0, 0, 64, 8><<<dim3(BATCH / 128, CDIM / 128, 2), 512, 0, stream>>>(
      c2_hi, rcT_hi, nullptr, P, nullptr, BATCH, CDIM, 512);
  reduce_cls<<<BATCH / 4, 256, 0, stream>>>(P, r2c_b, cls_w, cls_b, out);
}

// Round 14
// 428.776 us; speedup vs baseline: 1.0380x; 1.0380x over previous
//
#include <hip/hip_runtime.h>
#include <cstdint>

#define ND 16384
#define BATCH 4096
#define CDIM 768
#define E_DD 131072
#define FD 256

typedef unsigned short u16;
typedef u16 u16x4 __attribute__((ext_vector_type(4)));
typedef u16 u16x8 __attribute__((ext_vector_type(8)));
typedef short s16x8 __attribute__((ext_vector_type(8)));
typedef float f32x4 __attribute__((ext_vector_type(4)));

__device__ __forceinline__ u16 f2bf(float x) {
  union { float f; uint32_t u; } v; v.f = x;
  uint32_t r = v.u + 0x7fffu + ((v.u >> 16) & 1u);
  return (u16)(r >> 16);
}
__device__ __forceinline__ float bf2f(u16 h) {
  union { float f; uint32_t u; } v; v.u = ((uint32_t)h) << 16;
  return v.f;
}

// Direct global->LDS DMA, 16B per lane, LDS dest = wave-uniform base + lane*16.
#define GLOAD_LDS16(gp, lp)                                                   \
  __builtin_amdgcn_global_load_lds(                                           \
      (__attribute__((address_space(1))) void*)(gp),                          \
      (__attribute__((address_space(3))) void*)(lp), 16, 0, 0)

// ---------------------------------------------------------------------------
// MFMA GEMM core (device fn), 128x128 tile, 16x16x32 MFMA.
// NW = waves/block: 4 (2x2 wave grid, 64x64/wave) or 8 (2x4, 64x32/wave).
// DIRECT path: global_load_lds double-buffered, BKD-wide K-step, both-sides
// XOR slot swizzle (R2: 0 bank conflicts at BKD=64). Standalone GEMMs at
// BK64/NW8 sit at 913 TF == the m97-structure ceiling (m103: 912).
// Probed/excluded: counted-vmcnt (R3), XCD swizzle (R7), >4 waves/SIMD in
// one block (R8 +1%), gat merges (R5/R9), dual at BK64/NW8 (R13: 64KB arena
// cuts residency 5->2 blocks/CU — mixed kernels are residency-bound, not
// schedule-bound). Kept: concat-K hs (R12), prep merges (R4), scatter rider
// (R5), NW=8 standalone (R8), dual at BK32/NW4/32KB (R12 optimum).
// ---------------------------------------------------------------------------
template <int KS, int OUT_BF16, int RELU, int BIAS, int BKD, int NW>
__device__ __forceinline__ void gemm_core(
    int bx, int by, int bz,
    const u16* __restrict__ Ahi, const u16* __restrict__ Bhi,
    const float* __restrict__ bias,
    float* __restrict__ Cf, u16* __restrict__ Chi,
    int M, int N, int K, u16* AsB, u16* BsB) {
  constexpr int NTH = NW * 64;
  constexpr int WC = (NW == 8) ? 4 : 2;       // wave-grid cols
  constexpr int MT = 4;
  constexpr int NT = (NW == 8) ? 2 : 4;
  constexpr int BM = 128, BN = 128;

  const int t = threadIdx.x;
  const int bm0 = bx * BM, bn0 = by * BN;
  const int wid = t >> 6, lane = t & 63;
  const int quad = lane >> 4, l16 = lane & 15;
  const int wm0 = (wid / WC) * (MT * 16);
  const int wn0 = (wid % WC) * (NT * 16);

  const int chunk = K / KS;
  const int kbeg = (KS > 1) ? bz * chunk : 0;
  const int kend = kbeg + chunk;

  // Bias preload before the loop: off the epilogue critical path.
  float bvv[NT];
#pragma unroll
  for (int ni = 0; ni < NT; ++ni)
    bvv[ni] = BIAS ? bias[bn0 + wn0 + ni * 16 + l16] : 0.f;

  f32x4 acc[MT][NT];
#pragma unroll
  for (int i = 0; i < MT; ++i)
#pragma unroll
    for (int j = 0; j < NT; ++j) acc[i][j] = (f32x4){0.f, 0.f, 0.f, 0.f};

  // LDS: As/Bs [2][128][BKD] u16, linear in gload_lds lane order.
  // Swizzle: LDS 16B-slot (r, j) holds global chunk (r, j ^ (r & SM)).
  constexpr int SLOTS = BKD / 8;       // 16B chunks per row
  constexpr int SM = SLOTS - 1;
  constexpr int NLD = (BM * BKD) / (NTH * 8);  // gload_lds / thread / matrix
  auto stageA = [&](int buf, int kk) {
#pragma unroll
    for (int c = 0; c < NLD; ++c) {
      int s = t + NTH * c;
      int r = s / SLOTS, j = s % SLOTS;
      int jj = j ^ (r & SM);
      size_t goff = (size_t)(bm0 + r) * K + kk + jj * 8;
      int lofs = __builtin_amdgcn_readfirstlane((wid * 64 + NTH * c) * 8);
      GLOAD_LDS16(Ahi + goff, AsB + buf * (BM * BKD) + lofs);
    }
  };
  auto stageB = [&](int buf, int kk) {
#pragma unroll
    for (int c = 0; c < NLD; ++c) {
      int s = t + NTH * c;
      int r = s / SLOTS, j = s % SLOTS;
      int jj = j ^ (r & SM);
      size_t goff = (size_t)(bn0 + r) * K + kk + jj * 8;
      int lofs = __builtin_amdgcn_readfirstlane((wid * 64 + NTH * c) * 8);
      GLOAD_LDS16(Bhi + goff, BsB + buf * (BN * BKD) + lofs);
    }
  };
  const int rsw = l16 & SM;  // row&SM for all frag rows (rows ≡ l16 mod SLOTS)
  stageA(0, kbeg);
  stageB(0, kbeg);
  int cur = 0;
  for (int k0 = kbeg;;) {
    // __syncthreads drains vmcnt(0): buf[cur] staged, prior ds_reads done.
    __syncthreads();
    int kn = k0 + BKD;
    if (kn < kend) {  // prefetch next tile; in flight across the MFMA phase
      stageA(cur ^ 1, kn);
      stageB(cur ^ 1, kn);
    }
    const u16* Ab = AsB + cur * (BM * BKD);
    const u16* Bb = BsB + cur * (BN * BKD);
#pragma unroll
    for (int h = 0; h < BKD / 32; ++h) {
      s16x8 ah[MT], bh[NT];
#pragma unroll
      for (int mi = 0; mi < MT; ++mi)
        ah[mi] = *(const s16x8*)(Ab + (wm0 + mi * 16 + l16) * BKD +
                                 (((h * 4 + quad) ^ rsw) * 8));
#pragma unroll
      for (int ni = 0; ni < NT; ++ni)
        bh[ni] = *(const s16x8*)(Bb + (wn0 + ni * 16 + l16) * BKD +
                                 (((h * 4 + quad) ^ rsw) * 8));
#pragma unroll
      for (int mi = 0; mi < MT; ++mi)
#pragma unroll
        for (int ni = 0; ni < NT; ++ni)
          acc[mi][ni] = __builtin_amdgcn_mfma_f32_16x16x32_bf16(
              ah[mi], bh[ni], acc[mi][ni], 0, 0, 0);
    }
    k0 = kn;
    cur ^= 1;
    if (k0 >= kend) break;
  }

  // D row = quad*4 + reg, col = l16 (m89/m91 layout)
  float* Cp = (KS > 1) ? Cf + (size_t)bz * M * N : Cf;
#pragma unroll
  for (int mi = 0; mi < MT; ++mi) {
#pragma unroll
    for (int ni = 0; ni < NT; ++ni) {
      int row = bm0 + wm0 + mi * 16 + quad * 4;
      int col = bn0 + wn0 + ni * 16 + l16;
#pragma unroll
      for (int r = 0; r < 4; ++r) {
        float v = acc[mi][ni][r] + bvv[ni];
        if (RELU) v = fmaxf(v, 0.f);
        size_t o = (size_t)(row + r) * N + col;
        if (OUT_BF16) Chi[o] = f2bf(v);
        else Cp[o] = v;
      }
    }
  }
}

// Standalone GEMM kernel (no block swizzle — R7 lesson: default mapping wins).
template <int KS, int OUT_BF16, int RELU, int BIAS, int BKD, int NW>
__global__ __launch_bounds__(NW * 64) void mfma_gemm(
    const u16* __restrict__ Ahi, const u16* __restrict__ Bhi,
    const float* __restrict__ bias,
    float* __restrict__ Cf, u16* __restrict__ Chi,
    int M, int N, int K) {
  __shared__ __align__(16) u16 AsB[2 * 128 * BKD];
  __shared__ __align__(16) u16 BsB[2 * 128 * BKD];
  gemm_core<KS, OUT_BF16, RELU, BIAS, BKD, NW>(
      blockIdx.x, blockIdx.y, (KS > 1) ? (int)blockIdx.z : 0,
      Ahi, Bhi, bias, Cf, Chi, M, N, K, AsB, BsB);
}

// ---------------------------------------------------------------------------
// GAT aggregation body (device fn). One wave per dst; shuffle reductions;
// bf16 hs/out with wide loads (u16x8 + u16x4 = 24B/lane/row).
// ---------------------------------------------------------------------------
__device__ __forceinline__ void gat_body(
    int idx, int t,
    const u16* __restrict__ hs, const float* __restrict__ es,
    const float* __restrict__ ed, const int* __restrict__ offsets,
    const int* __restrict__ slots, const float* __restrict__ bias,
    const int* __restrict__ list, const int* __restrict__ cnt,
    u16* __restrict__ out) {
  if (idx >= *cnt) return;
  int d = list[idx];
  int lane = t & 63;
  int beg = offsets[d], end = offsets[d + 1];
  float edv = ed[d];
  float mx = -1e30f;
  for (int j = beg + lane; j < end; j += 64) {
    float e = es[slots[j]] + edv;
    e = e >= 0.f ? e : 0.2f * e;
    mx = fmaxf(mx, e);
  }
#pragma unroll
  for (int m = 32; m; m >>= 1) mx = fmaxf(mx, __shfl_xor(mx, m));
  float sm = 0.f;
  for (int j = beg + lane; j < end; j += 64) {
    float e = es[slots[j]] + edv;
    e = e >= 0.f ? e : 0.2f * e;
    sm += expf(e - mx);
  }
#pragma unroll
  for (int m = 32; m; m >>= 1) sm += __shfl_xor(sm, m);
  float inv = 1.f / (sm + 1e-16f);
  int c8 = lane * 8;          // cols 0..511
  int c4 = 512 + lane * 4;    // cols 512..767
  float a8[8] = {};
  float a4[4] = {};
  for (int j = beg; j < end; ++j) {
    int srcn = slots[j];
    float e = es[srcn] + edv;
    e = e >= 0.f ? e : 0.2f * e;
    float alpha = expf(e - mx) * inv;
    const u16* hrow = hs + (size_t)srcn * CDIM;
    u16x8 r8 = *(const u16x8*)(hrow + c8);
    u16x4 r4 = *(const u16x4*)(hrow + c4);
#pragma unroll
    for (int e2 = 0; e2 < 8; ++e2) a8[e2] = fmaf(alpha, bf2f(r8[e2]), a8[e2]);
#pragma unroll
    for (int e2 = 0; e2 < 4; ++e2) a4[e2] = fmaf(alpha, bf2f(r4[e2]), a4[e2]);
  }
  u16* orow = out + (size_t)d * CDIM;
  u16x8 o8;
  u16x4 o4;
#pragma unroll
  for (int e2 = 0; e2 < 8; ++e2) o8[e2] = f2bf(fmaxf(a8[e2] + bias[c8 + e2], 0.f));
#pragma unroll
  for (int e2 = 0; e2 < 4; ++e2) o4[e2] = f2bf(fmaxf(a4[e2] + bias[c4 + e2], 0.f));
  *(u16x8*)(orow + c8) = o8;
  *(u16x4*)(orow + c4) = o4;
}

__global__ __launch_bounds__(256) void gat_aggregate(
    const u16* __restrict__ hs, const float* __restrict__ es,
    const float* __restrict__ ed, const int* __restrict__ offsets,
    const int* __restrict__ slots, const float* __restrict__ bias,
    const int* __restrict__ list, const int* __restrict__ cnt,
    u16* __restrict__ out) {
  gat_body(blockIdx.x * 4 + (threadIdx.x >> 6), threadIdx.x,
           hs, es, ed, offsets, slots, bias, list, cnt, out);
}

// ---------------------------------------------------------------------------
// DUAL+SCATTER launch (R12 optimum: BK=32/NW=4/32KB arena -> ~5 blocks/CU
// heterogeneous residency, which R13 proved is the dual's binder):
// red1 (blocks 0..511) + hs2 concat-K (512..1279) + edge scatter (1280..1791).
// ---------------------------------------------------------------------------
__global__ __launch_bounds__(256) void dual_gemm_red1_hs_scatter(
    const u16* __restrict__ cn, const u16* __restrict__ r1T,
    const float* __restrict__ red1_b, u16* __restrict__ c1,
    const u16* __restrict__ x2, const u16* __restrict__ wsrcT2,
    u16* __restrict__ hs,
    const int* __restrict__ src, const int* __restrict__ dst,
    int* __restrict__ cursor, int* __restrict__ slots) {
  __shared__ __align__(16) u16 SMEM[16384];  // 32 KB
  int b = blockIdx.x;
  if (b < 512) {
    // red1: M=4096, N=2048, K=896; grid 32 x 16 (DIRECT gload_lds, BK=32)
    gemm_core<1, 1, 1, 1, 32, 4>(b & 31, b >> 5, 0, cn, r1T, red1_b,
                                 nullptr, c1, BATCH, 2048, 896,
                                 SMEM, SMEM + 2 * 128 * 32);
  } else if (b < 1280) {
    // hs2: M=16384, N=768, K=512 (concat hi||lo); grid 128 x 6, DIRECT BK=32
    int b2 = b - 512;
    gemm_core<1, 1, 0, 0, 32, 4>(b2 & 127, b2 >> 7, 0, x2, wsrcT2, nullptr,
                                 nullptr, hs, ND, CDIM, 512,
                                 SMEM, SMEM + 2 * 128 * 32);
  } else {
    // scatter: CSR edge placement
    int e = (b - 1280) * 256 + threadIdx.x;
    if (e < E_DD) {
      int pos = atomicAdd(&cursor[dst[e]], 1);
      slots[pos] = src[e];
    }
  }
}

// ---------------------------------------------------------------------------
// Split-K reduce: sum KS fp32 partials, +bias, relu, round to bf16.
// ---------------------------------------------------------------------------
template <int KS>
__global__ void reduce_split_ks(const float* __restrict__ P,
                                const float* __restrict__ bias,
                                u16* __restrict__ Chi, int M, int N) {
  int i = blockIdx.x * 256 + threadIdx.x;
  int total = (M * N) >> 2;
  if (i >= total) return;
  f32x4 s = ((const f32x4*)P)[i];
#pragma unroll
  for (int z = 1; z < KS; ++z) s += ((const f32x4*)P)[(size_t)z * total + i];
  int col = (i * 4) % N;
  f32x4 bv = *(const f32x4*)(bias + col);
  u16x4 h;
#pragma unroll
  for (int e = 0; e < 4; ++e) h[e] = f2bf(fmaxf(s[e] + bv[e], 0.f));
  *(u16x4*)&Chi[i * 4] = h;
}

// ---------------------------------------------------------------------------
// r2c reduce fused with classifier. One wave per row.
// ---------------------------------------------------------------------------
__global__ void reduce_cls(const float* __restrict__ P,
                           const float* __restrict__ bias,
                           const float* __restrict__ clsw,
                           const float* __restrict__ clsb,
                           float* __restrict__ out) {
  int row = blockIdx.x * 4 + (threadIdx.x >> 6);
  int lane = threadIdx.x & 63;
  const f32x4* p0 = (const f32x4*)(P + (size_t)row * CDIM);
  const f32x4* p1 = (const f32x4*)(P + (size_t)BATCH * CDIM + (size_t)row * CDIM);
  float s0 = 0.f, s1 = 0.f;
#pragma unroll
  for (int i = 0; i < 3; ++i) {
    int c4 = lane + 64 * i;
    f32x4 a = p0[c4] + p1[c4];
    f32x4 bv = *(const f32x4*)(bias + c4 * 4);
#pragma unroll
    for (int e = 0; e < 4; ++e) {
      float h = fmaxf(a[e] + bv[e], 0.f);
      int c = c4 * 4 + e;
      s0 = fmaf(h, clsw[c * 2 + 0], s0);
      s1 = fmaf(h, clsw[c * 2 + 1], s1);
    }
  }
#pragma unroll
  for (int m = 32; m; m >>= 1) {
    s0 += __shfl_xor(s0, m);
    s1 += __shfl_xor(s1, m);
  }
  if (lane == 0) {
    out[row * 2 + 0] = s0 + clsb[0];
    out[row * 2 + 1] = s1 + clsb[1];
  }
}

// ---------------------------------------------------------------------------
// Weight-transpose descriptors: W fp32 [K][N] -> bf16 [N][Kpad].
// dup=1: additionally write each value at k+K (builds B2=[B||B], Kpad=2K).
// ---------------------------------------------------------------------------
struct TDesc {
  const float* W;
  u16* Th;
  int K, N, Kpad, start, dup;
};
struct TPack { TDesc d[7]; };

// ---------------------------------------------------------------------------
// PREP1 (merged, independent ops): blocks [0,11328) 7 weight transposes;
// [11328,11584) wvec; [11584,11648) csr-init; [11648,15744) cell l2norm.
// ---------------------------------------------------------------------------
#define P1_T 11328
#define P1_W (P1_T + 256)
#define P1_I (P1_W + 64)
__global__ __launch_bounds__(256) void prep1(
    TPack p,
    const float* __restrict__ Wsrc, const float* __restrict__ Wdst,
    const float* __restrict__ a_s, const float* __restrict__ a_d,
    float* __restrict__ wsv, float* __restrict__ wdv,
    int* __restrict__ counts, int* __restrict__ mask, int* __restrict__ cnt,
    const float* __restrict__ cellf, u16* __restrict__ cn_hi) {
  __shared__ __align__(16) float S[1088];  // 4352 B arena (max branch: 32x33 tile)
  int b = blockIdx.x;
  int t = threadIdx.x;
  if (b < P1_T) {
    // --- weight transpose ---
    float (*tile)[33] = (float(*)[33])S;
    int mi = 0;
#pragma unroll
    for (int i = 1; i < 7; ++i)
      if (b >= p.d[i].start) mi = i;
    TDesc dd = p.d[mi];
    int rel = b - dd.start;
    int tilesX = dd.dup ? (dd.K / 32) : (dd.Kpad / 32);
    int k0 = (rel % tilesX) * 32, n0 = (rel / tilesX) * 32;
    int tx = t & 31, ty = t >> 5;
#pragma unroll
    for (int i = 0; i < 4; ++i) {
      int k = k0 + ty + 8 * i, n = n0 + tx;
      tile[ty + 8 * i][tx] = (k < dd.K && n < dd.N) ? dd.W[(size_t)k * dd.N + n] : 0.f;
    }
    __syncthreads();
#pragma unroll
    for (int i = 0; i < 4; ++i) {
      int n = n0 + ty + 8 * i, k = k0 + tx;
      if (n < dd.N) {
        u16 v = f2bf(tile[tx][ty + 8 * i]);
        dd.Th[(size_t)n * dd.Kpad + k] = v;
        if (dd.dup) dd.Th[(size_t)n * dd.Kpad + k + dd.K] = v;
      }
    }
  } else if (b < P1_W) {
    // --- wvec: wsv[k] = W_src[k,:].a_src ; wdv[k] = W_dst[k,:].a_dst ---
    int k = b - P1_T;
    float* rs = S;
    float* rd = S + 256;
    float s = 0.f, d = 0.f;
    for (int c = t; c < CDIM; c += 256) {
      s += Wsrc[(size_t)k * CDIM + c] * a_s[c];
      d += Wdst[(size_t)k * CDIM + c] * a_d[c];
    }
    rs[t] = s; rd[t] = d;
    __syncthreads();
    for (int st = 128; st; st >>= 1) {
      if (t < st) { rs[t] += rs[t + st]; rd[t] += rd[t + st]; }
      __syncthreads();
    }
    if (t == 0) { wsv[k] = rs[0]; wdv[k] = rd[0]; }
  } else if (b < P1_I) {
    // --- csr init: counts=1 (self loop), mask=0, cnt=0 ---
    int i = (b - P1_W) * 256 + t;
    if (i < ND) { counts[i] = 1; mask[i] = 0; }
    if (i == 0) *cnt = 0;
  } else {
    // --- cell l2norm -> bf16 [BATCH][896], zero pad 890..896 ---
    int row = b - P1_I;
    float* red = S;
    const float* irow = cellf + (size_t)row * 890;
    float s = 0.f;
    for (int c = t; c < 890; c += 256) { float v = irow[c]; s += v * v; }
    red[t] = s;
    __syncthreads();
    for (int st = 128; st; st >>= 1) {
      if (t < st) red[t] += red[t + st];
      __syncthreads();
    }
    float inv = 1.f / fmaxf(sqrtf(red[0]), 1e-12f);
    for (int c = t; c < 896; c += 256) {
      float v = (c < 890) ? irow[c] * inv : 0.f;
      cn_hi[(size_t)row * 896 + c] = f2bf(v);
    }
  }
}

// ---------------------------------------------------------------------------
// PREP2 (needs prep1): blocks [0,4096) esed (needs wvec) + x2 hi/lo split
// (rides along); [4096,4112) mark; [4112,4624) count_edges.
// ---------------------------------------------------------------------------
#define P2_E (ND * FD / 1024)          // 4096
#define P2_M (P2_E + BATCH / 256)      // 4112
__global__ __launch_bounds__(256) void prep2(
    const float* __restrict__ x, const float* __restrict__ wsv,
    const float* __restrict__ wdv, float* __restrict__ es, float* __restrict__ ed,
    u16* __restrict__ x2,
    const int* __restrict__ d1, const int* __restrict__ d2, int* __restrict__ mask,
    const int* __restrict__ dst, int* __restrict__ counts) {
  int b = blockIdx.x, t = threadIdx.x;
  if (b < P2_E) {
    // --- esed: es[row]=x[row].wsv, ed[row]=x[row].wdv — one wave per row ---
    int i = b * 256 + t;  // float4 index
    int lane = t & 63;
    int row = i >> 6;
    int c4 = lane * 4;
    f32x4 v = ((const f32x4*)x)[i];
    f32x4 ws = *(const f32x4*)(wsv + c4);
    f32x4 wd = *(const f32x4*)(wdv + c4);
    float a = v[0] * ws[0] + v[1] * ws[1] + v[2] * ws[2] + v[3] * ws[3];
    float bb = v[0] * wd[0] + v[1] * wd[1] + v[2] * wd[2] + v[3] * wd[3];
    // hi/lo split for the concat-K hs GEMM (identical values to old split2p)
    u16x4 hi, lo;
#pragma unroll
    for (int e = 0; e < 4; ++e) {
      u16 h = f2bf(v[e]);
      hi[e] = h;
      lo[e] = f2bf(v[e] - bf2f(h));
    }
    *(u16x4*)(x2 + (size_t)row * 512 + c4) = hi;
    *(u16x4*)(x2 + (size_t)row * 512 + 256 + c4) = lo;
#pragma unroll
    for (int m = 32; m; m >>= 1) {
      a += __shfl_xor(a, m);
      bb += __shfl_xor(bb, m);
    }
    if (lane == 0) { es[row] = a; ed[row] = bb; }
  } else if (b < P2_M) {
    // --- mark needed dsts ---
    int i = (b - P2_E) * 256 + t;
    mask[d1[i]] = 1;
    mask[d2[i]] = 1;
  } else {
    // --- count edges per dst ---
    int e = (b - P2_M) * 256 + t;
    atomicAdd(&counts[dst[e]], 1);
  }
}

// ---------------------------------------------------------------------------
// PREP3 (needs prep2), 512 threads: blocks [0,32) compact; block 32 scan
// (+ self-loop head placement + cursor init).
// ---------------------------------------------------------------------------
__global__ __launch_bounds__(512) void prep3(
    const int* __restrict__ mask, int* __restrict__ cnt, int* __restrict__ list,
    const int* __restrict__ counts, int* __restrict__ offsets,
    int* __restrict__ cursor, int* __restrict__ slots) {
  __shared__ int part[512];
  int b = blockIdx.x, t = threadIdx.x;
  if (b < 32) {
    int i = b * 512 + t;
    if (mask[i]) {
      int pos = atomicAdd(cnt, 1);
      list[pos] = i;
    }
  } else {
    int base = t * 32;
    int s = 0;
    for (int i = 0; i < 32; ++i) s += counts[base + i];
    part[t] = s;
    __syncthreads();
    if (t == 0) {
      int run = 0;
      for (int i = 0; i < 512; ++i) { int tmp = part[i]; part[i] = run; run += tmp; }
      offsets[ND] = run;
    }
    __syncthreads();
    int run = part[t];
    for (int i = 0; i < 32; ++i) {
      int d = base + i;
      offsets[d] = run;
      slots[run] = d;
      cursor[d] = run + 1;
      run += counts[d];
    }
  }
}

// hidden = l2norm(concat(drug[d1], drug[d2], cell3)) -> bf16 [B][3072]
__global__ __launch_bounds__(256) void hidden_build_bf16(
    const u16* __restrict__ drug, const u16* __restrict__ c3,
    const int* __restrict__ d1, const int* __restrict__ d2,
    u16* __restrict__ hhi) {
  int row = blockIdx.x;
  int t = threadIdx.x;
  const u16* s1 = drug + (size_t)d1[row] * CDIM;
  const u16* s2 = drug + (size_t)d2[row] * CDIM;
  const u16* s3 = c3 + (size_t)row * (2 * CDIM);
  float vals[12];
  float ss = 0.f;
#pragma unroll
  for (int i = 0; i < 12; ++i) {
    int c = t + 256 * i;
    float v;
    if (i < 3)      v = bf2f(s1[c]);
    else if (i < 6) v = bf2f(s2[c - CDIM]);
    else            v = bf2f(s3[c - 2 * CDIM]);
    vals[i] = v;
    ss += v * v;
  }
  __shared__ float red[256];
  red[t] = ss;
  __syncthreads();
  for (int st = 128; st; st >>= 1) {
    if (t < st) red[t] += red[t + st];
    __syncthreads();
  }
  float inv = 1.f / fmaxf(sqrtf(red[0]), 1e-12f);
  u16* hrow_h = hhi + (size_t)row * (4 * CDIM);
#pragma unroll
  for (int i = 0; i < 12; ++i) hrow_h[t + 256 * i] = f2bf(vals[i] * inv);
}

// ---------------------------------------------------------------------------
extern "C" void kernel_launch(void* const* d_in, const int* in_sizes, int n_in,
                              void* d_out, int out_size, void* d_ws, size_t ws_size,
                              hipStream_t stream) {
  const float* x_drug   = (const float*)d_in[0];
  const float* cellf    = (const float*)d_in[2];
  const float* W_src_dd = (const float*)d_in[3];
  const float* W_dst_dd = (const float*)d_in[4];
  const float* a_src_dd = (const float*)d_in[5];
  const float* a_dst_dd = (const float*)d_in[6];
  const float* b_dd     = (const float*)d_in[7];
  const float* red1_w = (const float*)d_in[18];
  const float* red1_b = (const float*)d_in[19];
  const float* red2_w = (const float*)d_in[20];
  const float* red2_b = (const float*)d_in[21];
  const float* red3_w = (const float*)d_in[22];
  const float* red3_b = (const float*)d_in[23];
  const float* r2a_w  = (const float*)d_in[24];
  const float* r2a_b  = (const float*)d_in[25];
  const float* r2b_w  = (const float*)d_in[26];
  const float* r2b_b  = (const float*)d_in[27];
  const float* r2c_w  = (const float*)d_in[28];
  const float* r2c_b  = (const float*)d_in[29];
  const float* cls_w  = (const float*)d_in[30];
  const float* cls_b  = (const float*)d_in[31];
  const int* drug1_id = (const int*)d_in[32];
  const int* drug2_id = (const int*)d_in[33];
  const int* ei_dd    = (const int*)d_in[34];
  float* out = (float*)d_out;

  const int* dd_src = ei_dd;
  const int* dd_dst = ei_dd + E_DD;

  char* w = (char*)d_ws;
  size_t off = 0;
  auto alloc = [&](size_t bytes) -> char* {
    char* p = w + off;
    off = (off + bytes + 255) & ~(size_t)255;
    return p;
  };
  // bf16 intermediates (all re-rounded downstream; validated error ladder)
  u16* hs   = (u16*)alloc((size_t)ND * CDIM * 2);            // reused as hidden bf16
  u16* drug = (u16*)alloc((size_t)ND * CDIM * 2);
  u16* c3   = (u16*)alloc((size_t)BATCH * 2 * CDIM * 2);
  float* P  = (float*)alloc((size_t)4 * BATCH * 512 * 4);    // split-K partials
  u16* hid_hi = hs;  // alias: ND*CDIM == BATCH*4*CDIM
  // bf16 activations
  u16* cn_hi = (u16*)alloc((size_t)BATCH * 896 * 2);
  u16* c1_hi = (u16*)alloc((size_t)BATCH * 2048 * 2);        // shared with h1
  u16* c2_hi = (u16*)alloc((size_t)BATCH * 512 * 2);         // shared with h2
  // x_drug hi/lo concat [ND][512] for the hs concat-K GEMM (R12)
  u16* x2 = (u16*)alloc((size_t)ND * 512 * 2);
  // transposed weights [N][Kpad] — single bf16
  u16* wsrcT2 = (u16*)alloc((size_t)CDIM * 512 * 2);         // B2 = [B||B]
  u16* r1T_hi = (u16*)alloc((size_t)2048 * 896 * 2);
  u16* r2T_hi = (u16*)alloc((size_t)512 * 2048 * 2);
  u16* r3T_hi = (u16*)alloc((size_t)1536 * 512 * 2);
  u16* raT_hi = (u16*)alloc((size_t)2048 * 3072 * 2);
  u16* rbT_hi = (u16*)alloc((size_t)512 * 2048 * 2);
  u16* rcT_hi = (u16*)alloc((size_t)768 * 512 * 2);
  // GAT scalars / CSR / dst-compaction
  float* es  = (float*)alloc((size_t)ND * 4);
  float* ed  = (float*)alloc((size_t)ND * 4);
  float* wsv = (float*)alloc(FD * 4);
  float* wdv = (float*)alloc(FD * 4);
  int* counts  = (int*)alloc((size_t)ND * 4);
  int* offsets = (int*)alloc((size_t)(ND + 1) * 4);
  int* cursor  = (int*)alloc((size_t)ND * 4);
  int* slots   = (int*)alloc((size_t)(E_DD + ND) * 4);
  int* mask    = (int*)alloc((size_t)ND * 4);
  int* list    = (int*)alloc((size_t)ND * 4);
  int* cnt     = (int*)alloc(256);
  (void)ws_size; (void)n_in; (void)in_sizes; (void)out_size;

  // --- prep1: 7 transposes + wvec + csr-init + cell l2norm (one launch) ---
  // d[0] builds B2=[B||B] via dup (192 blocks: tilesX = K/32 = 8).
  TPack tp;
  tp.d[0] = {W_src_dd, wsrcT2, 256, 768, 512, 0, 1};
  tp.d[1] = {red1_w, r1T_hi, 890, 2048, 896, 192, 0};
  tp.d[2] = {red2_w, r2T_hi, 2048, 512, 2048, 1984, 0};
  tp.d[3] = {red3_w, r3T_hi, 512, 1536, 512, 3008, 0};
  tp.d[4] = {r2a_w, raT_hi, 3072, 2048, 3072, 3776, 0};
  tp.d[5] = {r2b_w, rbT_hi, 2048, 512, 2048, 9920, 0};
  tp.d[6] = {r2c_w, rcT_hi, 512, 768, 512, 10944, 0};
  prep1<<<15744, 256, 0, stream>>>(tp, W_src_dd, W_dst_dd, a_src_dd, a_dst_dd,
                                   wsv, wdv, counts, mask, cnt, cellf, cn_hi);

  // --- prep2: esed + x2 hi/lo split + mark + count (one launch) ---
  prep2<<<4624, 256, 0, stream>>>(x_drug, wsv, wdv, es, ed, x2, drug1_id,
                                  drug2_id, mask, dd_dst, counts);

  // --- prep3: compact + scan (one launch, 512 threads) ---
  prep3<<<33, 512, 0, stream>>>(mask, cnt, list, counts, offsets, cursor, slots);

  // --- DUAL+SCATTER: red1 + hs2 (concat-K DIRECT) + edge scatter ---
  dual_gemm_red1_hs_scatter<<<1792, 256, 0, stream>>>(
      cn_hi, r1T_hi, red1_b, c1_hi, x2, wsrcT2, hs,
      dd_src, dd_dst, cursor, slots);

  // --- cell MLP tail (8-wave blocks: 4 waves/SIMD latency hiding) ---
  mfma_gemm<4, 0, 0, 0, 64, 8><<<dim3(BATCH / 128, 512 / 128, 4), 512, 0, stream>>>(
      c1_hi, r2T_hi, nullptr, P, nullptr, BATCH, 512, 2048);
  reduce_split_ks<4><<<BATCH * 512 / 1024, 256, 0, stream>>>(P, red2_b, c2_hi, BATCH, 512);
  mfma_gemm<1, 1, 1, 1, 64, 8><<<dim3(BATCH / 128, 1536 / 128), 512, 0, stream>>>(
      c2_hi, r3T_hi, red3_b, nullptr, c3, BATCH, 1536, 512);

  // --- GAT aggregation (softmax-weighted gather over CSR) ---
  gat_aggregate<<<ND / 4, 256, 0, stream>>>(hs, es, ed, offsets, slots, b_dd, list, cnt, drug);

  // --- gather + concat + l2norm -> bf16 (hidden aliases hs) ---
  hidden_build_bf16<<<BATCH, 256, 0, stream>>>(drug, c3, drug1_id, drug2_id, hid_hi);

  // --- head MLP (8-wave blocks) ---
  mfma_gemm<1, 1, 1, 1, 64, 8><<<dim3(BATCH / 128, 2048 / 128), 512, 0, stream>>>(
      hid_hi, raT_hi, r2a_b, nullptr, c1_hi, BATCH, 2048, 3072);
  mfma_gemm<4, 0, 0, 0, 64, 8><<<dim3(BATCH / 128, 512 / 128, 4), 512, 0, stream>>>(
      c1_hi, rbT_hi, nullptr, P, nullptr, BATCH, 512, 2048);
  reduce_split_ks<4><<<BATCH * 512 / 1024, 256, 0, stream>>>(P, r2b_b, c2_hi, BATCH, 512);
  mfma_gemm<2, 0, 0, 0, 64, 8><<<dim3(BATCH / 128, CDIM / 128, 2), 512, 0, stream>>>(
      c2_hi, rcT_hi, nullptr, P, nullptr, BATCH, CDIM, 512);
  reduce_cls<<<BATCH / 4, 256, 0, stream>>>(P, r2c_b, cls_w, cls_b, out);
}